// Round 3
// baseline (602.987 us; speedup 1.0000x reference)
//
#include <hip/hip_runtime.h>

#define NNODES 50000
#define NEDGES 800000
#define HH 4
#define DD 64
#define FEAT 256   // HH*DD
#define NB ((NNODES + 255) / 256)
#define MPAD 50048 // 391 * 128
#define SLSTRIDE ((size_t)NNODES * 32)  // f16 elems per feature-slice plane

typedef __attribute__((ext_vector_type(8))) _Float16 frag16;  // 8 f16 (4 VGPRs)
typedef __attribute__((ext_vector_type(4))) float frag_cd;    // 4 fp32
typedef __attribute__((ext_vector_type(4))) _Float16 h4v;     // 8-byte f16 vector

// ---------- combined prep: x->fp16 A' + both W->fp16 B'^T in one launch ----------
__global__ __launch_bounds__(256) void prep_kernel(
    const float* __restrict__ x, const float* __restrict__ W1,
    const float* __restrict__ W2, _Float16* __restrict__ Ap,
    _Float16* __restrict__ Bp1, _Float16* __restrict__ Bp2, int M) {
  int b = blockIdx.x;
  if (b < MPAD / 2) {
    int id = b * 256 + threadIdx.x;       // MPAD*128 quads
    int m = id >> 7;
    int k4 = (id & 127) << 2;
    float4 v = make_float4(0.f, 0.f, 0.f, 0.f);
    if (m < M) v = *(const float4*)&x[(size_t)m * 512 + k4];
    h4v o;
    o[0] = (_Float16)v.x; o[1] = (_Float16)v.y;
    o[2] = (_Float16)v.z; o[3] = (_Float16)v.w;
    *(h4v*)&Ap[(size_t)m * 512 + k4] = o;
  } else {
    int idx = (b - MPAD / 2) * 256 + threadIdx.x;  // (512+256)*256 elems
    if (idx < 512 * 256) {
      int k = idx >> 8, n = idx & 255;
      Bp1[(size_t)n * 512 + k] = (_Float16)W1[idx];
    } else {
      idx -= 512 * 256;
      int k = idx >> 8, n = idx & 255;
      Bp2[(size_t)n * 256 + k] = (_Float16)W2[idx];
    }
  }
}

// ---------- single-product fp16 MFMA GEMM (BK=64, XOR-swizzled LDS) ----------
// featb is stored SLICE-MAJOR: featb[slice][row][32] (slice = col>>5), so the
// gather kernel's per-XCD working set is one contiguous 3.2 MB plane.
__global__ __launch_bounds__(256) void mfma_gemm_kernel(
    const _Float16* __restrict__ Ap, const _Float16* __restrict__ Bp,
    _Float16* __restrict__ featb, const float* __restrict__ al,
    const float* __restrict__ ar, float* __restrict__ elp,
    float* __restrict__ erp, int M, int K) {
  __shared__ _Float16 As[128 * 64];  // 16 KB
  __shared__ _Float16 Bs[128 * 64];  // 16 KB
  const int tid = threadIdx.x;
  const int w = tid >> 6, lane = tid & 63;
  const int q = lane >> 4, ln = lane & 15;
  const int rowBase = blockIdx.x * 128;
  const int colBase = blockIdx.y * 128;
  const int wm = (w >> 1) * 64;
  const int wn = (w & 1) * 64;

  frag_cd acc[4][4] = {};

  const int i1 = K >> 6;  // BK=64
  const int srow8 = lane >> 3;               // 0..7
  const int scg = ((lane & 7) ^ srow8) * 8;  // swizzled global chunk (f16 units)
  const int sw = ln & 7;                     // read-side swizzle key

  for (int it = 0; it < i1; ++it) {
    const int kk = it << 6;
    __syncthreads();
#pragma unroll
    for (int j = 0; j < 4; ++j) {
      int rloc = w * 32 + j * 8 + srow8;
      __builtin_amdgcn_global_load_lds(
          (const __attribute__((address_space(1))) void*)(Ap + (size_t)(rowBase + rloc) * K + kk + scg),
          (__attribute__((address_space(3))) void*)(&As[(w * 32 + j * 8) * 64 + lane * 8]), 16, 0, 0);
    }
#pragma unroll
    for (int j = 0; j < 4; ++j) {
      int rloc = w * 32 + j * 8 + srow8;
      __builtin_amdgcn_global_load_lds(
          (const __attribute__((address_space(1))) void*)(Bp + (size_t)(colBase + rloc) * K + kk + scg),
          (__attribute__((address_space(3))) void*)(&Bs[(w * 32 + j * 8) * 64 + lane * 8]), 16, 0, 0);
    }
    __syncthreads();

#pragma unroll
    for (int ksub = 0; ksub < 2; ++ksub) {
      const int slot = ((ksub * 4 + q) ^ sw) * 8;
      frag16 a[4], b[4];
#pragma unroll
      for (int i = 0; i < 4; ++i)
        a[i] = *(const frag16*)&As[(wm + i * 16 + ln) * 64 + slot];
#pragma unroll
      for (int j = 0; j < 4; ++j)
        b[j] = *(const frag16*)&Bs[(wn + j * 16 + ln) * 64 + slot];
#pragma unroll
      for (int i = 0; i < 4; ++i)
#pragma unroll
        for (int j = 0; j < 4; ++j)
          acc[i][j] = __builtin_amdgcn_mfma_f32_16x16x32_f16(a[i], b[j], acc[i][j], 0, 0, 0);
    }
  }

  // ---- f16 feat store, slice-major (D row = q*4+reg, col = ln) ----
#pragma unroll
  for (int i = 0; i < 4; ++i) {
    int rowg = rowBase + wm + i * 16 + q * 4;
#pragma unroll
    for (int r = 0; r < 4; ++r) {
      int row = rowg + r;
      if (row < M) {
#pragma unroll
        for (int j = 0; j < 4; ++j) {
          int col = colBase + wn + j * 16 + ln;
          featb[(size_t)(col >> 5) * SLSTRIDE + (size_t)row * 32 + (col & 31)] =
              (_Float16)acc[i][j][r];
        }
      }
    }
  }

  // ---- fused el/er: this wave's 64 cols == one head (exact fp32) ----
  const int h = (colBase + wn) >> 6;
  float alv[4], arv[4];
#pragma unroll
  for (int j = 0; j < 4; ++j) {
    alv[j] = al[h * DD + j * 16 + ln];
    arv[j] = ar[h * DD + j * 16 + ln];
  }
#pragma unroll
  for (int i = 0; i < 4; ++i) {
#pragma unroll
    for (int r = 0; r < 4; ++r) {
      float pl = 0.f, pr = 0.f;
#pragma unroll
      for (int j = 0; j < 4; ++j) {
        pl = fmaf(acc[i][j][r], alv[j], pl);
        pr = fmaf(acc[i][j][r], arv[j], pr);
      }
#pragma unroll
      for (int msk = 1; msk < 16; msk <<= 1) {
        pl += __shfl_xor(pl, msk);
        pr += __shfl_xor(pr, msk);
      }
      int row = rowBase + wm + i * 16 + q * 4 + r;
      if (ln == 0 && row < M) {
        elp[row * HH + h] = pl;
        erp[row * HH + h] = pr;
      }
    }
  }
}

// ---------- CSR build ----------
__global__ __launch_bounds__(256) void hist_kernel(const int* __restrict__ dst,
                                                   int* __restrict__ deg) {
  int e = blockIdx.x * 256 + threadIdx.x;
  if (e < NEDGES) atomicAdd(&deg[dst[e]], 1);
}

__global__ __launch_bounds__(256) void scan_block_kernel(const int* __restrict__ deg,
                                                         int* __restrict__ off,
                                                         int* __restrict__ bsum) {
  __shared__ int tmp[256];
  int b = blockIdx.x, t = threadIdx.x;
  int i = b * 256 + t;
  int v = (i < NNODES) ? deg[i] : 0;
  tmp[t] = v;
  __syncthreads();
  for (int s = 1; s < 256; s <<= 1) {
    int add = (t >= s) ? tmp[t - s] : 0;
    __syncthreads();
    tmp[t] += add;
    __syncthreads();
  }
  if (i < NNODES) off[i + 1] = tmp[t];
  if (t == 255) bsum[b] = tmp[255];
}

__global__ __launch_bounds__(256) void scan_top_kernel(int* __restrict__ bsum) {
  __shared__ int tmp[256];
  int t = threadIdx.x;
  int v = (t < NB) ? bsum[t] : 0;
  tmp[t] = v;
  __syncthreads();
  for (int s = 1; s < 256; s <<= 1) {
    int add = (t >= s) ? tmp[t - s] : 0;
    __syncthreads();
    tmp[t] += add;
    __syncthreads();
  }
  if (t < NB) bsum[t] = tmp[t] - v;
}

__global__ __launch_bounds__(256) void scan_add_kernel(int* __restrict__ off,
                                                       const int* __restrict__ bsum,
                                                       int* __restrict__ cursor) {
  int b = blockIdx.x, t = threadIdx.x;
  int i = b * 256 + t;
  if (i < NNODES) {
    int val = off[i + 1] + bsum[b];
    off[i + 1] = val;
    if (i + 1 < NNODES) cursor[i + 1] = val;
  }
  if (i == 0) { off[0] = 0; cursor[0] = 0; }
}

__global__ __launch_bounds__(256) void scatter_kernel(const int* __restrict__ src,
                                                      const int* __restrict__ dst,
                                                      int* __restrict__ cursor,
                                                      unsigned short* __restrict__ csr16) {
  int e = blockIdx.x * 256 + threadIdx.x;
  if (e >= NEDGES) return;
  int d = dst[e];
  int pos = atomicAdd(&cursor[d], 1);
  csr16[pos] = (unsigned short)src[e];
}

// ---------- per-node softmax weights -> wa[4][E] f16 (one wave per node) ----------
__global__ __launch_bounds__(256) void score_kernel(
    const int* __restrict__ off, const unsigned short* __restrict__ csr16,
    const float* __restrict__ el, const float* __restrict__ er,
    _Float16* __restrict__ wa) {
  const int w = threadIdx.x >> 6, lane = threadIdx.x & 63;
  const int n = blockIdx.x * 4 + w;  // NNODES = 4 * 12500 exactly
  const int beg = off[n];
  const int deg = off[n + 1] - beg;
  if (deg <= 0) return;
  const int h1 = lane & 3, j1 = lane >> 2;
  const float erd = er[n * HH + h1];
  if (deg <= 64) {
    float e[4], a[4];
    float m = -INFINITY;
#pragma unroll
    for (int p = 0; p < 4; ++p) {
      int j = j1 + p * 16;
      float ev = -INFINITY;
      if (j < deg) {
        int s = csr16[beg + j];
        ev = el[s * HH + h1] + erd;
        ev = ev > 0.f ? ev : 0.2f * ev;
      }
      e[p] = ev;
      m = fmaxf(m, ev);
    }
#pragma unroll
    for (int msk = 4; msk <= 32; msk <<= 1) m = fmaxf(m, __shfl_xor(m, msk));
    float ps = 0.f;
#pragma unroll
    for (int p = 0; p < 4; ++p) {
      a[p] = (j1 + p * 16 < deg) ? __expf(e[p] - m) : 0.f;
      ps += a[p];
    }
#pragma unroll
    for (int msk = 4; msk <= 32; msk <<= 1) ps += __shfl_xor(ps, msk);
    const float sinv = 1.f / ps;
#pragma unroll
    for (int p = 0; p < 4; ++p) {
      int j = j1 + p * 16;
      if (j < deg) wa[(size_t)h1 * NEDGES + beg + j] = (_Float16)(a[p] * sinv);
    }
  } else {
    // generic fallback (unreachable for Poisson(16) but kept for correctness)
    float m = -INFINITY;
    for (int j = j1; j < deg; j += 16) {
      int s = csr16[beg + j];
      float ev = el[s * HH + h1] + erd;
      ev = ev > 0.f ? ev : 0.2f * ev;
      m = fmaxf(m, ev);
    }
#pragma unroll
    for (int msk = 4; msk <= 32; msk <<= 1) m = fmaxf(m, __shfl_xor(m, msk));
    float ps = 0.f;
    for (int j = j1; j < deg; j += 16) {
      int s = csr16[beg + j];
      float ev = el[s * HH + h1] + erd;
      ev = ev > 0.f ? ev : 0.2f * ev;
      ps += __expf(ev - m);
    }
#pragma unroll
    for (int msk = 4; msk <= 32; msk <<= 1) ps += __shfl_xor(ps, msk);
    const float sinv = 1.f / ps;
    for (int j = j1; j < deg; j += 16) {
      int s = csr16[beg + j];
      float ev = el[s * HH + h1] + erd;
      ev = ev > 0.f ? ev : 0.2f * ev;
      wa[(size_t)h1 * NEDGES + beg + j] = (_Float16)(__expf(ev - m) * sinv);
    }
  }
}

// ---------- XCD-sliced gather v2: one WAVE per (node, slice) ----------
// slice = blockIdx.x & 7 pins a 3.2 MB featb plane to one XCD's L2.
// Per wave: stage this node's (src id, weight) pairs in LDS as int2 (one
// ds_read_b64 broadcast per 8-lane edge-group, no shfl), then gather 16
// edges/iter (2 independent dwordx2 loads in flight). Lane = (es = lane>>3
// edge-in-group, f4 = (lane&7)*4 feature quad). Fold es-groups at the end.
template <int LAYER>
__global__ __launch_bounds__(256) void slice_gather_kernel(
    const int* __restrict__ off, const unsigned short* __restrict__ csr16,
    const _Float16* __restrict__ wa, const _Float16* __restrict__ featb,
    float* __restrict__ tmp, _Float16* __restrict__ outs) {
  __shared__ int2 sSA[4][64];  // [wave][edge] {src id, weight bits}
  const int w = threadIdx.x >> 6, lane = threadIdx.x & 63;
  const int sl = blockIdx.x & 7;   // feature slice == XCD (round-robin dispatch)
  const int nb = blockIdx.x >> 3;
  const int n = nb * 4 + w;        // NNODES = 4 * 12500 exactly
  const int es = lane >> 3, f4 = (lane & 7) << 2;
  const int h = sl >> 1;           // head of this slice
  const _Float16* __restrict__ fp = featb + (size_t)sl * SLSTRIDE;
  const _Float16* __restrict__ wap = wa + (size_t)h * NEDGES;

  const int beg = off[n];
  const int deg = off[n + 1] - beg;

  float acc0 = 0.f, acc1 = 0.f, acc2 = 0.f, acc3 = 0.f;

  for (int base = 0; base < deg; base += 64) {
    // ---- stage up to 64 edges (zero-padded: s=0 row is hot, a=0) ----
    int e = base + lane;
    int s = 0;
    float a = 0.f;
    if (e < deg) {
      s = __builtin_nontemporal_load(&csr16[beg + e]);
      a = (float)__builtin_nontemporal_load(&wap[beg + e]);
    }
    sSA[w][lane] = make_int2(s << 5, __float_as_int(a));  // pre-shifted row offset
    int rem = deg - base;
    if (rem > 64) rem = 64;
    // ---- 16 edges per iteration: 2 independent loads in flight ----
    for (int jb = 0; jb < rem; jb += 16) {
      int2 p0 = sSA[w][jb + es];
      int2 p1 = sSA[w][jb + 8 + es];
      float a0 = __int_as_float(p0.y), a1 = __int_as_float(p1.y);
      h4v u0 = *(const h4v*)&fp[p0.x + f4];
      h4v u1 = *(const h4v*)&fp[p1.x + f4];
      acc0 = fmaf(a0, (float)u0[0], acc0);
      acc1 = fmaf(a0, (float)u0[1], acc1);
      acc2 = fmaf(a0, (float)u0[2], acc2);
      acc3 = fmaf(a0, (float)u0[3], acc3);
      acc0 = fmaf(a1, (float)u1[0], acc0);
      acc1 = fmaf(a1, (float)u1[1], acc1);
      acc2 = fmaf(a1, (float)u1[2], acc2);
      acc3 = fmaf(a1, (float)u1[3], acc3);
    }
  }

  // ---- fold the 8 edge-groups ----
#pragma unroll
  for (int msk = 8; msk <= 32; msk <<= 1) {
    acc0 += __shfl_xor(acc0, msk);
    acc1 += __shfl_xor(acc1, msk);
    acc2 += __shfl_xor(acc2, msk);
    acc3 += __shfl_xor(acc3, msk);
  }

  if (lane >= 8) return;  // es==0 lanes hold the result
  if (LAYER == 1) {
    h4v o;
    float v0 = acc0, v1 = acc1, v2 = acc2, v3 = acc3;
    o[0] = (_Float16)(v0 > 0.f ? v0 : (__expf(v0) - 1.f));  // ELU
    o[1] = (_Float16)(v1 > 0.f ? v1 : (__expf(v1) - 1.f));
    o[2] = (_Float16)(v2 > 0.f ? v2 : (__expf(v2) - 1.f));
    o[3] = (_Float16)(v3 > 0.f ? v3 : (__expf(v3) - 1.f));
    *(h4v*)&outs[(size_t)n * 256 + sl * 32 + f4] = o;  // next layer's A' row
  } else {
    float4 o = make_float4(acc0, acc1, acc2, acc3);
    *(float4*)&tmp[(size_t)n * 256 + sl * 32 + f4] = o;  // per-slice partials
  }
}

// ---------- layer-2 head mean: out[n][d] = 0.25 * sum_h tmp[n][2h+(d>>5)][d&31] ----------
__global__ __launch_bounds__(256) void head_mean_kernel(const float* __restrict__ tmp,
                                                        float* __restrict__ outp) {
  int i = blockIdx.x * 256 + threadIdx.x;  // exact: NNODES*64 = 12500*256
  int n = i >> 6, d = i & 63;
  const float* base = tmp + (size_t)n * 256 + (d >> 5) * 32 + (d & 31);
  outp[i] = 0.25f * (base[0] + base[64] + base[128] + base[192]);
}

extern "C" void kernel_launch(void* const* d_in, const int* in_sizes, int n_in,
                              void* d_out, int out_size, void* d_ws, size_t ws_size,
                              hipStream_t stream) {
  const float* x   = (const float*)d_in[0];
  const int*   src = (const int*)d_in[1];
  const int*   dst = (const int*)d_in[2];
  const float* W1  = (const float*)d_in[3];
  const float* al1 = (const float*)d_in[4];
  const float* ar1 = (const float*)d_in[5];
  const float* W2  = (const float*)d_in[6];
  const float* al2 = (const float*)d_in[7];
  const float* ar2 = (const float*)d_in[8];
  float* out = (float*)d_out;

  // workspace layout
  float* ws = (float*)d_ws;
  float* el = ws;                           // NNODES*HH
  float* er = el + NNODES * HH;             // NNODES*HH
  int* deg     = (int*)(er + NNODES * HH);  // NNODES
  int* off     = deg + NNODES;              // NNODES+1
  int* cursor  = off + NNODES + 1;          // NNODES
  int* bsum    = cursor + NNODES;           // 256
  unsigned short* csr16 = (unsigned short*)(bsum + 256);  // NEDGES u16
  _Float16* wa = (_Float16*)(csr16 + NEDGES);             // 4*NEDGES f16
  uintptr_t p = ((uintptr_t)(wa + (size_t)4 * NEDGES) + 63) & ~(uintptr_t)63;
  _Float16* featb = (_Float16*)p;                  // 8 slice planes (25.6 MB)
  _Float16* Apr = featb + (size_t)8 * SLSTRIDE;
  Apr = (_Float16*)(((uintptr_t)Apr + 63) & ~(uintptr_t)63);  // MPAD*512 f16
  _Float16* Bpr1 = Apr + (size_t)MPAD * 512;       // 256*512 f16
  _Float16* Bpr2 = Bpr1 + 256 * 512;               // 256*256 f16
  // layer-2 partials alias Apr (dead after GEMM2 reads it): 50000*256 f32 fits
  float* tmp = (float*)Apr;

  const int edgeBlocks = (NEDGES + 255) / 256;
  dim3 mfmaGrid(MPAD / 128, 2);
  const int gatGrid = (NNODES / 4) * 8;  // 12500 node-blocks x 8 slices

  // ---------- CSR build (shared by both layers) ----------
  hipMemsetAsync(deg, 0, NNODES * sizeof(int), stream);
  hist_kernel<<<edgeBlocks, 256, 0, stream>>>(dst, deg);
  scan_block_kernel<<<NB, 256, 0, stream>>>(deg, off, bsum);
  scan_top_kernel<<<1, 256, 0, stream>>>(bsum);
  scan_add_kernel<<<NB, 256, 0, stream>>>(off, bsum, cursor);
  scatter_kernel<<<edgeBlocks, 256, 0, stream>>>(src, dst, cursor, csr16);

  // ---------- prep (fp16 A' + both B', one launch) ----------
  prep_kernel<<<MPAD / 2 + 768, 256, 0, stream>>>(x, W1, W2, Apr, Bpr1, Bpr2, NNODES);

  // ---------- layer 1 : K=512 ----------
  mfma_gemm_kernel<<<mfmaGrid, 256, 0, stream>>>(Apr, Bpr1, featb, al1, ar1, el, er, NNODES, 512);
  score_kernel<<<NNODES / 4, 256, 0, stream>>>(off, csr16, el, er, wa);
  slice_gather_kernel<1><<<gatGrid, 256, 0, stream>>>(off, csr16, wa, featb, nullptr, Apr);

  // ---------- layer 2 : K=256 ----------
  mfma_gemm_kernel<<<mfmaGrid, 256, 0, stream>>>(Apr, Bpr2, featb, al2, ar2, el, er, NNODES, 256);
  score_kernel<<<NNODES / 4, 256, 0, stream>>>(off, csr16, el, er, wa);
  slice_gather_kernel<2><<<gatGrid, 256, 0, stream>>>(off, csr16, wa, featb, tmp, nullptr);
  head_mean_kernel<<<NNODES / 4, 256, 0, stream>>>(tmp, out);
}

// Round 4
// 475.893 us; speedup vs baseline: 1.2671x; 1.2671x over previous
//
#include <hip/hip_runtime.h>

#define NNODES 50000
#define NEDGES 800000
#define HH 4
#define DD 64
#define FEAT 256   // HH*DD
#define NB ((NNODES + 255) / 256)
#define MPAD 50048 // 391 * 128
#define SLSTRIDE ((size_t)NNODES * 32)   // f16 elems per feature-slice plane
#define EPAD (NEDGES + 8 * NNODES)       // padded-CSR capacity (8-multiple per node)

typedef __attribute__((ext_vector_type(8))) _Float16 frag16;  // 8 f16 (4 VGPRs)
typedef __attribute__((ext_vector_type(4))) float frag_cd;    // 4 fp32
typedef __attribute__((ext_vector_type(4))) _Float16 h4v;     // 8-byte f16 vector
typedef __attribute__((ext_vector_type(8))) _Float16 h8v;     // 16-byte f16 vector
typedef __attribute__((ext_vector_type(8))) unsigned short u16x8;  // 16-byte id vec

// ---------- combined prep: x->fp16 A' + both W->fp16 B'^T in one launch ----------
__global__ __launch_bounds__(256) void prep_kernel(
    const float* __restrict__ x, const float* __restrict__ W1,
    const float* __restrict__ W2, _Float16* __restrict__ Ap,
    _Float16* __restrict__ Bp1, _Float16* __restrict__ Bp2, int M) {
  int b = blockIdx.x;
  if (b < MPAD / 2) {
    int id = b * 256 + threadIdx.x;       // MPAD*128 quads
    int m = id >> 7;
    int k4 = (id & 127) << 2;
    float4 v = make_float4(0.f, 0.f, 0.f, 0.f);
    if (m < M) v = *(const float4*)&x[(size_t)m * 512 + k4];
    h4v o;
    o[0] = (_Float16)v.x; o[1] = (_Float16)v.y;
    o[2] = (_Float16)v.z; o[3] = (_Float16)v.w;
    *(h4v*)&Ap[(size_t)m * 512 + k4] = o;
  } else {
    int idx = (b - MPAD / 2) * 256 + threadIdx.x;  // (512+256)*256 elems
    if (idx < 512 * 256) {
      int k = idx >> 8, n = idx & 255;
      Bp1[(size_t)n * 512 + k] = (_Float16)W1[idx];
    } else {
      idx -= 512 * 256;
      int k = idx >> 8, n = idx & 255;
      Bp2[(size_t)n * 256 + k] = (_Float16)W2[idx];
    }
  }
}

// ---------- single-product fp16 MFMA GEMM (BK=64, XOR-swizzled LDS) ----------
// featb is stored SLICE-MAJOR: featb[slice][row][32] (slice = col>>5), so the
// gather kernel's per-XCD working set is one contiguous 3.2 MB plane.
__global__ __launch_bounds__(256) void mfma_gemm_kernel(
    const _Float16* __restrict__ Ap, const _Float16* __restrict__ Bp,
    _Float16* __restrict__ featb, const float* __restrict__ al,
    const float* __restrict__ ar, float* __restrict__ elp,
    float* __restrict__ erp, int M, int K) {
  __shared__ _Float16 As[128 * 64];  // 16 KB
  __shared__ _Float16 Bs[128 * 64];  // 16 KB
  const int tid = threadIdx.x;
  const int w = tid >> 6, lane = tid & 63;
  const int q = lane >> 4, ln = lane & 15;
  const int rowBase = blockIdx.x * 128;
  const int colBase = blockIdx.y * 128;
  const int wm = (w >> 1) * 64;
  const int wn = (w & 1) * 64;

  frag_cd acc[4][4] = {};

  const int i1 = K >> 6;  // BK=64
  const int srow8 = lane >> 3;               // 0..7
  const int scg = ((lane & 7) ^ srow8) * 8;  // swizzled global chunk (f16 units)
  const int sw = ln & 7;                     // read-side swizzle key

  for (int it = 0; it < i1; ++it) {
    const int kk = it << 6;
    __syncthreads();
#pragma unroll
    for (int j = 0; j < 4; ++j) {
      int rloc = w * 32 + j * 8 + srow8;
      __builtin_amdgcn_global_load_lds(
          (const __attribute__((address_space(1))) void*)(Ap + (size_t)(rowBase + rloc) * K + kk + scg),
          (__attribute__((address_space(3))) void*)(&As[(w * 32 + j * 8) * 64 + lane * 8]), 16, 0, 0);
    }
#pragma unroll
    for (int j = 0; j < 4; ++j) {
      int rloc = w * 32 + j * 8 + srow8;
      __builtin_amdgcn_global_load_lds(
          (const __attribute__((address_space(1))) void*)(Bp + (size_t)(colBase + rloc) * K + kk + scg),
          (__attribute__((address_space(3))) void*)(&Bs[(w * 32 + j * 8) * 64 + lane * 8]), 16, 0, 0);
    }
    __syncthreads();

#pragma unroll
    for (int ksub = 0; ksub < 2; ++ksub) {
      const int slot = ((ksub * 4 + q) ^ sw) * 8;
      frag16 a[4], b[4];
#pragma unroll
      for (int i = 0; i < 4; ++i)
        a[i] = *(const frag16*)&As[(wm + i * 16 + ln) * 64 + slot];
#pragma unroll
      for (int j = 0; j < 4; ++j)
        b[j] = *(const frag16*)&Bs[(wn + j * 16 + ln) * 64 + slot];
#pragma unroll
      for (int i = 0; i < 4; ++i)
#pragma unroll
        for (int j = 0; j < 4; ++j)
          acc[i][j] = __builtin_amdgcn_mfma_f32_16x16x32_f16(a[i], b[j], acc[i][j], 0, 0, 0);
    }
  }

  // ---- f16 feat store, slice-major (D row = q*4+reg, col = ln) ----
#pragma unroll
  for (int i = 0; i < 4; ++i) {
    int rowg = rowBase + wm + i * 16 + q * 4;
#pragma unroll
    for (int r = 0; r < 4; ++r) {
      int row = rowg + r;
      if (row < M) {
#pragma unroll
        for (int j = 0; j < 4; ++j) {
          int col = colBase + wn + j * 16 + ln;
          featb[(size_t)(col >> 5) * SLSTRIDE + (size_t)row * 32 + (col & 31)] =
              (_Float16)acc[i][j][r];
        }
      }
    }
  }

  // ---- fused el/er: this wave's 64 cols == one head (exact fp32) ----
  const int h = (colBase + wn) >> 6;
  float alv[4], arv[4];
#pragma unroll
  for (int j = 0; j < 4; ++j) {
    alv[j] = al[h * DD + j * 16 + ln];
    arv[j] = ar[h * DD + j * 16 + ln];
  }
#pragma unroll
  for (int i = 0; i < 4; ++i) {
#pragma unroll
    for (int r = 0; r < 4; ++r) {
      float pl = 0.f, pr = 0.f;
#pragma unroll
      for (int j = 0; j < 4; ++j) {
        pl = fmaf(acc[i][j][r], alv[j], pl);
        pr = fmaf(acc[i][j][r], arv[j], pr);
      }
#pragma unroll
      for (int msk = 1; msk < 16; msk <<= 1) {
        pl += __shfl_xor(pl, msk);
        pr += __shfl_xor(pr, msk);
      }
      int row = rowBase + wm + i * 16 + q * 4 + r;
      if (ln == 0 && row < M) {
        elp[row * HH + h] = pl;
        erp[row * HH + h] = pr;
      }
    }
  }
}

// ---------- CSR build (padded: each node's slot count rounded up to 8) ----------
__global__ __launch_bounds__(256) void hist_kernel(const int* __restrict__ dst,
                                                   int* __restrict__ deg) {
  int e = blockIdx.x * 256 + threadIdx.x;
  if (e < NEDGES) atomicAdd(&deg[dst[e]], 1);
}

__global__ __launch_bounds__(256) void scan_block_kernel(const int* __restrict__ deg,
                                                         int* __restrict__ poff,
                                                         int* __restrict__ bsum) {
  __shared__ int tmp[256];
  int b = blockIdx.x, t = threadIdx.x;
  int i = b * 256 + t;
  int v = (i < NNODES) ? ((deg[i] + 7) & ~7) : 0;  // pad to 8-multiple
  tmp[t] = v;
  __syncthreads();
  for (int s = 1; s < 256; s <<= 1) {
    int add = (t >= s) ? tmp[t - s] : 0;
    __syncthreads();
    tmp[t] += add;
    __syncthreads();
  }
  if (i < NNODES) poff[i + 1] = tmp[t];
  if (t == 255) bsum[b] = tmp[255];
}

__global__ __launch_bounds__(256) void scan_top_kernel(int* __restrict__ bsum) {
  __shared__ int tmp[256];
  int t = threadIdx.x;
  int v = (t < NB) ? bsum[t] : 0;
  tmp[t] = v;
  __syncthreads();
  for (int s = 1; s < 256; s <<= 1) {
    int add = (t >= s) ? tmp[t - s] : 0;
    __syncthreads();
    tmp[t] += add;
    __syncthreads();
  }
  if (t < NB) bsum[t] = tmp[t] - v;
}

__global__ __launch_bounds__(256) void scan_add_kernel(int* __restrict__ poff,
                                                       const int* __restrict__ bsum,
                                                       int* __restrict__ cursor) {
  int b = blockIdx.x, t = threadIdx.x;
  int i = b * 256 + t;
  if (i < NNODES) {
    int val = poff[i + 1] + bsum[b];
    poff[i + 1] = val;
    if (i + 1 < NNODES) cursor[i + 1] = val;
  }
  if (i == 0) { poff[0] = 0; cursor[0] = 0; }
}

__global__ __launch_bounds__(256) void scatter_kernel(const int* __restrict__ src,
                                                      const int* __restrict__ dst,
                                                      int* __restrict__ cursor,
                                                      unsigned short* __restrict__ csr16) {
  int e = blockIdx.x * 256 + threadIdx.x;
  if (e >= NEDGES) return;
  int d = dst[e];
  int pos = atomicAdd(&cursor[d], 1);
  csr16[pos] = (unsigned short)src[e];
}

// ---------- per-node softmax weights -> wa[4][EPAD] f16 (one wave per node) ----------
// Pad slots [deg, degpad) get weight 0 (ids were memset to 0) so the gather
// can run unconditionally over 8-edge chunks.
__global__ __launch_bounds__(256) void score_kernel(
    const int* __restrict__ deg_arr, const int* __restrict__ poff,
    const unsigned short* __restrict__ csr16, const float* __restrict__ el,
    const float* __restrict__ er, _Float16* __restrict__ wa) {
  const int w = threadIdx.x >> 6, lane = threadIdx.x & 63;
  const int n = blockIdx.x * 4 + w;  // NNODES = 4 * 12500 exactly
  const int beg = poff[n];
  const int degpad = poff[n + 1] - beg;
  if (degpad <= 0) return;
  const int deg = deg_arr[n];
  const int h1 = lane & 3, j1 = lane >> 2;
  const float erd = er[n * HH + h1];
  if (deg <= 64) {
    float e[4], a[4];
    float m = -INFINITY;
#pragma unroll
    for (int p = 0; p < 4; ++p) {
      int j = j1 + p * 16;
      float ev = -INFINITY;
      if (j < deg) {
        int s = csr16[beg + j];
        ev = el[s * HH + h1] + erd;
        ev = ev > 0.f ? ev : 0.2f * ev;
      }
      e[p] = ev;
      m = fmaxf(m, ev);
    }
#pragma unroll
    for (int msk = 4; msk <= 32; msk <<= 1) m = fmaxf(m, __shfl_xor(m, msk));
    float ps = 0.f;
#pragma unroll
    for (int p = 0; p < 4; ++p) {
      a[p] = (j1 + p * 16 < deg) ? __expf(e[p] - m) : 0.f;
      ps += a[p];
    }
#pragma unroll
    for (int msk = 4; msk <= 32; msk <<= 1) ps += __shfl_xor(ps, msk);
    const float sinv = 1.f / ps;
#pragma unroll
    for (int p = 0; p < 4; ++p) {
      int j = j1 + p * 16;
      if (j < degpad) wa[(size_t)h1 * EPAD + beg + j] = (_Float16)(a[p] * sinv);
    }
  } else {
    // generic fallback (unreachable for Poisson(16) but kept for correctness)
    float m = -INFINITY;
    for (int j = j1; j < deg; j += 16) {
      int s = csr16[beg + j];
      float ev = el[s * HH + h1] + erd;
      ev = ev > 0.f ? ev : 0.2f * ev;
      m = fmaxf(m, ev);
    }
#pragma unroll
    for (int msk = 4; msk <= 32; msk <<= 1) m = fmaxf(m, __shfl_xor(m, msk));
    float ps = 0.f;
    for (int j = j1; j < deg; j += 16) {
      int s = csr16[beg + j];
      float ev = el[s * HH + h1] + erd;
      ev = ev > 0.f ? ev : 0.2f * ev;
      ps += __expf(ev - m);
    }
#pragma unroll
    for (int msk = 4; msk <= 32; msk <<= 1) ps += __shfl_xor(ps, msk);
    const float sinv = 1.f / ps;
    for (int j = j1; j < deg; j += 16) {
      int s = csr16[beg + j];
      float ev = el[s * HH + h1] + erd;
      ev = ev > 0.f ? ev : 0.2f * ev;
      wa[(size_t)h1 * EPAD + beg + j] = (_Float16)(__expf(ev - m) * sinv);
    }
    // zero the pad slots (<=7) in all 4 head planes
    if (j1 < degpad - deg)
      wa[(size_t)h1 * EPAD + beg + deg + j1] = (_Float16)0.f;
  }
}

// ---------- XCD-sliced gather v3: 8-lane group per (node, slice) ----------
// slice = blockIdx.x & 7 pins a 3.2 MB featb plane to one XCD's L2.
// Wave = 8 nodes; group g = lane>>3 owns node n, lane owns features
// [f4, f4+4) of the 32-feature slice -> accumulator is final (no fold, no
// LDS). Edges come in 8-chunks: ids (ushort8) + weights (half8) are single
// 16 B broadcast loads (aligned: poff is 8-multiple); pad slots have id 0 /
// weight 0. Next chunk is prefetched before the current fma block.
template <int LAYER>
__global__ __launch_bounds__(256) void slice_gather_kernel(
    const int* __restrict__ poff, const unsigned short* __restrict__ csr16,
    const _Float16* __restrict__ wa, const _Float16* __restrict__ featb,
    float* __restrict__ tmp, _Float16* __restrict__ outs) {
  const int lane = threadIdx.x & 63;
  const int w = threadIdx.x >> 6;
  const int sl = blockIdx.x & 7;   // feature slice == XCD (round-robin dispatch)
  const int nb = blockIdx.x >> 3;
  const int g = lane >> 3;         // node group within wave
  const int f4 = (lane & 7) << 2;  // feature quad within slice
  const int n = nb * 32 + w * 8 + g;
  const int h = sl >> 1;           // head of this slice
  const _Float16* __restrict__ fp = featb + (size_t)sl * SLSTRIDE;
  const _Float16* __restrict__ wap = wa + (size_t)h * EPAD;

  int beg = 0, end = 0;
  if (n < NNODES) { beg = poff[n]; end = poff[n + 1]; }
  const int nch = (end - beg) >> 3;  // 8-edge chunks (uniform within group)

  const u16x8* __restrict__ idp = (const u16x8*)(csr16 + beg);
  const h8v* __restrict__ wvp = (const h8v*)(wap + beg);

  float acc0 = 0.f, acc1 = 0.f, acc2 = 0.f, acc3 = 0.f;

  u16x8 idv;
  h8v wv;
  if (nch > 0) { idv = idp[0]; wv = wvp[0]; }
  for (int c = 0; c < nch; ++c) {
    u16x8 idc = idv;
    h8v wc = wv;
    if (c + 1 < nch) { idv = idp[c + 1]; wv = wvp[c + 1]; }  // prefetch
#pragma unroll
    for (int e = 0; e < 8; ++e) {
      int s = idc[e];
      float a = (float)wc[e];
      h4v u = *(const h4v*)&fp[(s << 5) + f4];
      acc0 = fmaf(a, (float)u[0], acc0);
      acc1 = fmaf(a, (float)u[1], acc1);
      acc2 = fmaf(a, (float)u[2], acc2);
      acc3 = fmaf(a, (float)u[3], acc3);
    }
  }

  if (n >= NNODES) return;
  if (LAYER == 1) {
    h4v o;
    o[0] = (_Float16)(acc0 > 0.f ? acc0 : (__expf(acc0) - 1.f));  // ELU
    o[1] = (_Float16)(acc1 > 0.f ? acc1 : (__expf(acc1) - 1.f));
    o[2] = (_Float16)(acc2 > 0.f ? acc2 : (__expf(acc2) - 1.f));
    o[3] = (_Float16)(acc3 > 0.f ? acc3 : (__expf(acc3) - 1.f));
    *(h4v*)&outs[(size_t)n * 256 + sl * 32 + f4] = o;  // next layer's A' row
  } else {
    float4 o = make_float4(acc0, acc1, acc2, acc3);
    *(float4*)&tmp[(size_t)n * 256 + sl * 32 + f4] = o;  // per-slice partials
  }
}

// ---------- layer-2 head mean: out[n][d] = 0.25 * sum_h tmp[n][2h+(d>>5)][d&31] ----------
__global__ __launch_bounds__(256) void head_mean_kernel(const float* __restrict__ tmp,
                                                        float* __restrict__ outp) {
  int i = blockIdx.x * 256 + threadIdx.x;  // exact: NNODES*64 = 12500*256
  int n = i >> 6, d = i & 63;
  const float* base = tmp + (size_t)n * 256 + (d >> 5) * 32 + (d & 31);
  outp[i] = 0.25f * (base[0] + base[64] + base[128] + base[192]);
}

extern "C" void kernel_launch(void* const* d_in, const int* in_sizes, int n_in,
                              void* d_out, int out_size, void* d_ws, size_t ws_size,
                              hipStream_t stream) {
  const float* x   = (const float*)d_in[0];
  const int*   src = (const int*)d_in[1];
  const int*   dst = (const int*)d_in[2];
  const float* W1  = (const float*)d_in[3];
  const float* al1 = (const float*)d_in[4];
  const float* ar1 = (const float*)d_in[5];
  const float* W2  = (const float*)d_in[6];
  const float* al2 = (const float*)d_in[7];
  const float* ar2 = (const float*)d_in[8];
  float* out = (float*)d_out;

  // workspace layout
  float* ws = (float*)d_ws;
  float* el = ws;                           // NNODES*HH
  float* er = el + NNODES * HH;             // NNODES*HH
  int* deg     = (int*)(er + NNODES * HH);  // NNODES
  int* poff    = deg + NNODES;              // NNODES+1
  int* cursor  = poff + NNODES + 1;         // NNODES
  int* bsum    = cursor + NNODES;           // 256
  unsigned short* csr16 = (unsigned short*)(bsum + 256);  // EPAD u16
  _Float16* wa = (_Float16*)(csr16 + EPAD);               // 4*EPAD f16
  uintptr_t p = ((uintptr_t)(wa + (size_t)4 * EPAD) + 63) & ~(uintptr_t)63;
  _Float16* featb = (_Float16*)p;                  // 8 slice planes (25.6 MB)
  _Float16* Apr = featb + (size_t)8 * SLSTRIDE;
  Apr = (_Float16*)(((uintptr_t)Apr + 63) & ~(uintptr_t)63);  // MPAD*512 f16
  _Float16* Bpr1 = Apr + (size_t)MPAD * 512;       // 256*512 f16
  _Float16* Bpr2 = Bpr1 + 256 * 512;               // 256*256 f16
  // layer-2 partials alias Apr (dead after GEMM2 reads it): 50000*256 f32 fits
  float* tmp = (float*)Apr;

  const int edgeBlocks = (NEDGES + 255) / 256;
  dim3 mfmaGrid(MPAD / 128, 2);
  const int gatGrid = ((NNODES + 31) / 32) * 8;  // 1563 node-blocks x 8 slices

  // ---------- CSR build (shared by both layers) ----------
  hipMemsetAsync(deg, 0, NNODES * sizeof(int), stream);
  hipMemsetAsync(csr16, 0, (size_t)EPAD * sizeof(unsigned short), stream);
  hist_kernel<<<edgeBlocks, 256, 0, stream>>>(dst, deg);
  scan_block_kernel<<<NB, 256, 0, stream>>>(deg, poff, bsum);
  scan_top_kernel<<<1, 256, 0, stream>>>(bsum);
  scan_add_kernel<<<NB, 256, 0, stream>>>(poff, bsum, cursor);
  scatter_kernel<<<edgeBlocks, 256, 0, stream>>>(src, dst, cursor, csr16);

  // ---------- prep (fp16 A' + both B', one launch) ----------
  prep_kernel<<<MPAD / 2 + 768, 256, 0, stream>>>(x, W1, W2, Apr, Bpr1, Bpr2, NNODES);

  // ---------- layer 1 : K=512 ----------
  mfma_gemm_kernel<<<mfmaGrid, 256, 0, stream>>>(Apr, Bpr1, featb, al1, ar1, el, er, NNODES, 512);
  score_kernel<<<NNODES / 4, 256, 0, stream>>>(deg, poff, csr16, el, er, wa);
  slice_gather_kernel<1><<<gatGrid, 256, 0, stream>>>(poff, csr16, wa, featb, nullptr, Apr);

  // ---------- layer 2 : K=256 ----------
  mfma_gemm_kernel<<<mfmaGrid, 256, 0, stream>>>(Apr, Bpr2, featb, al2, ar2, el, er, NNODES, 256);
  score_kernel<<<NNODES / 4, 256, 0, stream>>>(deg, poff, csr16, el, er, wa);
  slice_gather_kernel<2><<<gatGrid, 256, 0, stream>>>(poff, csr16, wa, featb, tmp, nullptr);
  head_mean_kernel<<<NNODES / 4, 256, 0, stream>>>(tmp, out);
}

// Round 5
// 409.668 us; speedup vs baseline: 1.4719x; 1.1617x over previous
//
#include <hip/hip_runtime.h>

#define NNODES 50000
#define NEDGES 800000
#define HH 4
#define DD 64
#define FEAT 256   // HH*DD
#define NB ((NNODES + 255) / 256)
#define MPAD 50048 // 391 * 128

typedef __attribute__((ext_vector_type(8))) _Float16 frag16;  // 8 f16 (4 VGPRs)
typedef __attribute__((ext_vector_type(4))) float frag_cd;    // 4 fp32
typedef __attribute__((ext_vector_type(4))) _Float16 h4v;     // 8-byte f16 vector
typedef __attribute__((ext_vector_type(8))) _Float16 h8v;     // 16-byte f16 vector

// ---------- prep: W1/W2 -> f16 B'^T only (x conversion is fused into GEMM1) ----------
__global__ __launch_bounds__(256) void prep_w_kernel(
    const float* __restrict__ W1, const float* __restrict__ W2,
    _Float16* __restrict__ Bp1, _Float16* __restrict__ Bp2) {
  int idx = blockIdx.x * 256 + threadIdx.x;  // (512+256)*256 elems, grid 768
  if (idx < 512 * 256) {
    int k = idx >> 8, n = idx & 255;
    Bp1[(size_t)n * 512 + k] = (_Float16)W1[idx];
  } else {
    idx -= 512 * 256;
    int k = idx >> 8, n = idx & 255;
    Bp2[(size_t)n * 256 + k] = (_Float16)W2[idx];
  }
}

// ---------- fp16 MFMA GEMM, 128x256 tile (full N per block), 8 waves ----------
// AF32=1: A is f32 x[M,512], converted to f16 during reg-staged LDS writes
//         (A read ONCE from HBM; prep-A pass and Apr*512 buffer eliminated).
// AF32=0: A is f16 Apr[M,K], staged via global_load_lds (R1 pattern).
// LDS layout (both As and Bs): slot s of row r holds global chunk s^(r&7)
// (chunk = 8 f16 = 16 B) -> conflict-free ds_read_b128 on the read side.
// featb[M,256] f16 row-major; el/er computed fused (exact fp32).
template <int AF32>
__global__ __launch_bounds__(512) void mfma_gemm_kernel(
    const void* __restrict__ Av, const _Float16* __restrict__ Bp,
    _Float16* __restrict__ featb, const float* __restrict__ al,
    const float* __restrict__ ar, float* __restrict__ elp,
    float* __restrict__ erp, int M, int K) {
  __shared__ _Float16 As[128 * 64];  // 16 KB
  __shared__ _Float16 Bs[256 * 64];  // 32 KB
  const int tid = threadIdx.x;
  const int w = tid >> 6, lane = tid & 63;
  const int q = lane >> 4, ln = lane & 15;
  const int rowBase = blockIdx.x * 128;
  const int wm = (w >> 2) * 64;      // 2 row-halves
  const int wn = (w & 3) * 64;       // 4 col-quarters (= heads)

  frag_cd acc[4][4] = {};

  const int i1 = K >> 6;  // BK=64
  const int srow8 = lane >> 3;               // 0..7
  const int scg = ((lane & 7) ^ srow8) * 8;  // swizzled global chunk (f16 units)
  const int sw = ln & 7;                     // read-side swizzle key

  // f32 A-staging map: thread t -> row r = t>>2, chunk-pair qq = t&3
  const int ar_ = tid >> 2, aq = tid & 3;
  const int as0 = ((aq * 2) ^ (ar_ & 7)) * 8;      // slot of chunk 2qq
  const int as1 = ((aq * 2 + 1) ^ (ar_ & 7)) * 8;  // slot of chunk 2qq+1

  for (int it = 0; it < i1; ++it) {
    const int kk = it << 6;
    __syncthreads();
    if constexpr (AF32) {
      const float* __restrict__ x = (const float*)Av;
      float4 v0, v1, v2, v3;
      v0 = v1 = v2 = v3 = make_float4(0.f, 0.f, 0.f, 0.f);
      int xrow = rowBase + ar_;
      if (xrow < M) {
        const float4* xp = (const float4*)(x + (size_t)xrow * 512 + kk + aq * 16);
        v0 = xp[0]; v1 = xp[1]; v2 = xp[2]; v3 = xp[3];
      }
      frag16 f0, f1;
      f0[0] = (_Float16)v0.x; f0[1] = (_Float16)v0.y;
      f0[2] = (_Float16)v0.z; f0[3] = (_Float16)v0.w;
      f0[4] = (_Float16)v1.x; f0[5] = (_Float16)v1.y;
      f0[6] = (_Float16)v1.z; f0[7] = (_Float16)v1.w;
      f1[0] = (_Float16)v2.x; f1[1] = (_Float16)v2.y;
      f1[2] = (_Float16)v2.z; f1[3] = (_Float16)v2.w;
      f1[4] = (_Float16)v3.x; f1[5] = (_Float16)v3.y;
      f1[6] = (_Float16)v3.z; f1[7] = (_Float16)v3.w;
      *(frag16*)&As[ar_ * 64 + as0] = f0;
      *(frag16*)&As[ar_ * 64 + as1] = f1;
    } else {
      const _Float16* __restrict__ Ap = (const _Float16*)Av;
#pragma unroll
      for (int j = 0; j < 2; ++j) {
        int rloc = w * 16 + j * 8 + srow8;
        __builtin_amdgcn_global_load_lds(
            (const __attribute__((address_space(1))) void*)(Ap + (size_t)(rowBase + rloc) * K + kk + scg),
            (__attribute__((address_space(3))) void*)(&As[(w * 16 + j * 8) * 64 + lane * 8]), 16, 0, 0);
      }
    }
#pragma unroll
    for (int j = 0; j < 4; ++j) {
      int rloc = w * 32 + j * 8 + srow8;
      __builtin_amdgcn_global_load_lds(
          (const __attribute__((address_space(1))) void*)(Bp + (size_t)rloc * K + kk + scg),
          (__attribute__((address_space(3))) void*)(&Bs[(w * 32 + j * 8) * 64 + lane * 8]), 16, 0, 0);
    }
    __syncthreads();

#pragma unroll
    for (int ksub = 0; ksub < 2; ++ksub) {
      const int slot = ((ksub * 4 + q) ^ sw) * 8;
      frag16 a[4], b[4];
#pragma unroll
      for (int i = 0; i < 4; ++i)
        a[i] = *(const frag16*)&As[(wm + i * 16 + ln) * 64 + slot];
#pragma unroll
      for (int j = 0; j < 4; ++j)
        b[j] = *(const frag16*)&Bs[(wn + j * 16 + ln) * 64 + slot];
#pragma unroll
      for (int i = 0; i < 4; ++i)
#pragma unroll
        for (int j = 0; j < 4; ++j)
          acc[i][j] = __builtin_amdgcn_mfma_f32_16x16x32_f16(a[i], b[j], acc[i][j], 0, 0, 0);
    }
  }

  // ---- f16 feat store, row-major (D row = q*4+reg, col = ln) ----
#pragma unroll
  for (int i = 0; i < 4; ++i) {
    int rowg = rowBase + wm + i * 16 + q * 4;
#pragma unroll
    for (int r = 0; r < 4; ++r) {
      int row = rowg + r;
      if (row < M) {
#pragma unroll
        for (int j = 0; j < 4; ++j) {
          int col = wn + j * 16 + ln;
          featb[(size_t)row * 256 + col] = (_Float16)acc[i][j][r];
        }
      }
    }
  }

  // ---- fused el/er: this wave's 64 cols == one head (exact fp32) ----
  const int h = wn >> 6;
  float alv[4], arv[4];
#pragma unroll
  for (int j = 0; j < 4; ++j) {
    alv[j] = al[h * DD + j * 16 + ln];
    arv[j] = ar[h * DD + j * 16 + ln];
  }
#pragma unroll
  for (int i = 0; i < 4; ++i) {
#pragma unroll
    for (int r = 0; r < 4; ++r) {
      float pl = 0.f, pr = 0.f;
#pragma unroll
      for (int j = 0; j < 4; ++j) {
        pl = fmaf(acc[i][j][r], alv[j], pl);
        pr = fmaf(acc[i][j][r], arv[j], pr);
      }
#pragma unroll
      for (int msk = 1; msk < 16; msk <<= 1) {
        pl += __shfl_xor(pl, msk);
        pr += __shfl_xor(pr, msk);
      }
      int row = rowBase + wm + i * 16 + q * 4 + r;
      if (ln == 0 && row < M) {
        elp[row * HH + h] = pl;
        erp[row * HH + h] = pr;
      }
    }
  }
}

// ---------- CSR build ----------
__global__ __launch_bounds__(256) void hist_kernel(const int* __restrict__ dst,
                                                   int* __restrict__ deg) {
  int e = blockIdx.x * 256 + threadIdx.x;
  if (e < NEDGES) atomicAdd(&deg[dst[e]], 1);
}

__global__ __launch_bounds__(256) void scan_block_kernel(const int* __restrict__ deg,
                                                         int* __restrict__ off,
                                                         int* __restrict__ bsum) {
  __shared__ int tmp[256];
  int b = blockIdx.x, t = threadIdx.x;
  int i = b * 256 + t;
  int v = (i < NNODES) ? deg[i] : 0;
  tmp[t] = v;
  __syncthreads();
  for (int s = 1; s < 256; s <<= 1) {
    int add = (t >= s) ? tmp[t - s] : 0;
    __syncthreads();
    tmp[t] += add;
    __syncthreads();
  }
  if (i < NNODES) off[i + 1] = tmp[t];
  if (t == 255) bsum[b] = tmp[255];
}

__global__ __launch_bounds__(256) void scan_top_kernel(int* __restrict__ bsum) {
  __shared__ int tmp[256];
  int t = threadIdx.x;
  int v = (t < NB) ? bsum[t] : 0;
  tmp[t] = v;
  __syncthreads();
  for (int s = 1; s < 256; s <<= 1) {
    int add = (t >= s) ? tmp[t - s] : 0;
    __syncthreads();
    tmp[t] += add;
    __syncthreads();
  }
  if (t < NB) bsum[t] = tmp[t] - v;
}

__global__ __launch_bounds__(256) void scan_add_kernel(int* __restrict__ off,
                                                       const int* __restrict__ bsum,
                                                       int* __restrict__ cursor) {
  int b = blockIdx.x, t = threadIdx.x;
  int i = b * 256 + t;
  if (i < NNODES) {
    int val = off[i + 1] + bsum[b];
    off[i + 1] = val;
    if (i + 1 < NNODES) cursor[i + 1] = val;
  }
  if (i == 0) { off[0] = 0; cursor[0] = 0; }
}

__global__ __launch_bounds__(256) void scatter_kernel(const int* __restrict__ src,
                                                      const int* __restrict__ dst,
                                                      int* __restrict__ cursor,
                                                      int* __restrict__ csr_src) {
  int e = blockIdx.x * 256 + threadIdx.x;
  if (e >= NEDGES) return;
  int d = dst[e];
  int pos = atomicAdd(&cursor[d], 1);
  csr_src[pos] = src[e];
}

// ---------- fused per-dst-node GAT: one WAVE per node, paired 16B gather ----------
// Phase 2 lane mapping: half = lane>>5 picks the edge of a pair; fl = lane&31
// owns features [fl*8, fl*8+8) (head fl>>3). Each lane loads h8v (16B) ->
// one dwordx4 instruction covers TWO edges' rows (1 KB/wave). Final
// shfl_xor(32) folds the two edge-halves.
template <int LAYER>
__global__ __launch_bounds__(256) void gat_agg_kernel(
    const int* __restrict__ off, const int* __restrict__ csr_src,
    const float* __restrict__ el, const float* __restrict__ er,
    const _Float16* __restrict__ featb, float* __restrict__ outp,
    _Float16* __restrict__ outs) {
  __shared__ float sA[4][HH][68];  // [wave][head][edge] normalized weights
  __shared__ int sS[4][64];        // [wave][edge] src ids
  const int w = threadIdx.x >> 6;
  const int lane = threadIdx.x & 63;
  const int n = blockIdx.x * 4 + w;   // NNODES = 4 * 12500 exactly
  const int beg = off[n];
  const int deg = off[n + 1] - beg;

  const int half = lane >> 5;   // which edge of the pair
  const int fl = lane & 31;     // feature block of 8
  const int fb = fl << 3;       // feature start (f16 units)
  const int hh = fl >> 3;       // head for this lane's features

  float acc[8] = {0.f, 0.f, 0.f, 0.f, 0.f, 0.f, 0.f, 0.f};

  if (deg > 0 && deg <= 64) {
    // ---- phase 1: scores once per (edge,head), shfl reductions ----
    const int h1 = lane & 3, j1 = lane >> 2;
    const float erd = er[n * HH + h1];
    float e[4], a[4];
    float m = -INFINITY;
#pragma unroll
    for (int p = 0; p < 4; ++p) {
      int j = j1 + p * 16;
      int s = 0;
      float ev = -INFINITY;
      if (j < deg) {
        s = csr_src[beg + j];
        ev = el[s * HH + h1] + erd;
        ev = ev > 0.f ? ev : 0.2f * ev;
      }
      if (h1 == 0) sS[w][j] = s;  // zero-pad beyond deg (row 0, weight 0)
      e[p] = ev;
      m = fmaxf(m, ev);
    }
#pragma unroll
    for (int msk = 4; msk <= 32; msk <<= 1) m = fmaxf(m, __shfl_xor(m, msk));
    float ps = 0.f;
#pragma unroll
    for (int p = 0; p < 4; ++p) {
      a[p] = (j1 + p * 16 < deg) ? __expf(e[p] - m) : 0.f;
      ps += a[p];
    }
#pragma unroll
    for (int msk = 4; msk <= 32; msk <<= 1) ps += __shfl_xor(ps, msk);
    const float sinv = 1.f / ps;
#pragma unroll
    for (int p = 0; p < 4; ++p) {
      int j = j1 + p * 16;
      sA[w][h1][j] = a[p] * sinv;  // zero for j >= deg (a[p] == 0)
    }

    // ---- phase 2: paired 16B gather (1 KB/wave per pair-load) ----
    const int deg2 = (deg + 1) & ~1;
    int j = 0;
    for (; j + 8 <= deg2; j += 8) {
      int s0 = sS[w][j + half];
      int s1 = sS[w][j + 2 + half];
      int s2 = sS[w][j + 4 + half];
      int s3 = sS[w][j + 6 + half];
      float a0 = sA[w][hh][j + half];
      float a1 = sA[w][hh][j + 2 + half];
      float a2 = sA[w][hh][j + 4 + half];
      float a3 = sA[w][hh][j + 6 + half];
      h8v u0 = *(const h8v*)&featb[(size_t)s0 * FEAT + fb];
      h8v u1 = *(const h8v*)&featb[(size_t)s1 * FEAT + fb];
      h8v u2 = *(const h8v*)&featb[(size_t)s2 * FEAT + fb];
      h8v u3 = *(const h8v*)&featb[(size_t)s3 * FEAT + fb];
#pragma unroll
      for (int c = 0; c < 8; ++c) acc[c] = fmaf(a0, (float)u0[c], acc[c]);
#pragma unroll
      for (int c = 0; c < 8; ++c) acc[c] = fmaf(a1, (float)u1[c], acc[c]);
#pragma unroll
      for (int c = 0; c < 8; ++c) acc[c] = fmaf(a2, (float)u2[c], acc[c]);
#pragma unroll
      for (int c = 0; c < 8; ++c) acc[c] = fmaf(a3, (float)u3[c], acc[c]);
    }
    for (; j < deg2; j += 2) {
      int s0 = sS[w][j + half];
      float a0 = sA[w][hh][j + half];
      h8v u0 = *(const h8v*)&featb[(size_t)s0 * FEAT + fb];
#pragma unroll
      for (int c = 0; c < 8; ++c) acc[c] = fmaf(a0, (float)u0[c], acc[c]);
    }
  } else if (deg > 64) {
    // ---- generic register-only fallback (unreachable for Poisson(16)) ----
    const int h1 = lane & 3, j1 = lane >> 2;
    const float erd = er[n * HH + h1];
    float m = -INFINITY;
    for (int j = j1; j < deg; j += 16) {
      int s = csr_src[beg + j];
      float ev = el[s * HH + h1] + erd;
      ev = ev > 0.f ? ev : 0.2f * ev;
      m = fmaxf(m, ev);
    }
#pragma unroll
    for (int msk = 4; msk <= 32; msk <<= 1) m = fmaxf(m, __shfl_xor(m, msk));
    float ps = 0.f;
    for (int j = j1; j < deg; j += 16) {
      int s = csr_src[beg + j];
      float ev = el[s * HH + h1] + erd;
      ev = ev > 0.f ? ev : 0.2f * ev;
      ps += __expf(ev - m);
    }
#pragma unroll
    for (int msk = 4; msk <= 32; msk <<= 1) ps += __shfl_xor(ps, msk);
    const float m2 = __shfl(m, hh);
    const float psinv2 = 1.f / __shfl(ps, hh);
    const float erd2 = er[n * HH + hh];
    // halves split even/odd edges; xor(32) fold below sums them
    for (int j = half; j < deg; j += 2) {
      int s = csr_src[beg + j];
      float ev = el[s * HH + hh] + erd2;
      ev = ev > 0.f ? ev : 0.2f * ev;
      float a0 = __expf(ev - m2) * psinv2;
      h8v u0 = *(const h8v*)&featb[(size_t)s * FEAT + fb];
#pragma unroll
      for (int c = 0; c < 8; ++c) acc[c] = fmaf(a0, (float)u0[c], acc[c]);
    }
  }

  // ---- fold the two edge-halves ----
#pragma unroll
  for (int c = 0; c < 8; ++c) acc[c] += __shfl_xor(acc[c], 32);

  // ---- epilogue ----
  if (LAYER == 1) {
    if (half == 0) {
      h8v o;
#pragma unroll
      for (int c = 0; c < 8; ++c) {
        float v = acc[c];
        v = v > 0.f ? v : (__expf(v) - 1.f);  // ELU
        o[c] = (_Float16)v;
      }
      *(h8v*)&outs[(size_t)n * 256 + fb] = o;  // next layer's A row (f16)
    }
  } else {
    // mean over heads: features f = fl*8+c, head = bits 3..4 of fl
#pragma unroll
    for (int c = 0; c < 8; ++c) {
      acc[c] += __shfl_xor(acc[c], 8);
      acc[c] += __shfl_xor(acc[c], 16);
    }
    if (lane < 8) {
      float4 o1 = make_float4(0.25f * acc[0], 0.25f * acc[1],
                              0.25f * acc[2], 0.25f * acc[3]);
      float4 o2 = make_float4(0.25f * acc[4], 0.25f * acc[5],
                              0.25f * acc[6], 0.25f * acc[7]);
      *(float4*)&outp[(size_t)n * DD + (lane << 3)] = o1;
      *(float4*)&outp[(size_t)n * DD + (lane << 3) + 4] = o2;
    }
  }
}

extern "C" void kernel_launch(void* const* d_in, const int* in_sizes, int n_in,
                              void* d_out, int out_size, void* d_ws, size_t ws_size,
                              hipStream_t stream) {
  const float* x   = (const float*)d_in[0];
  const int*   src = (const int*)d_in[1];
  const int*   dst = (const int*)d_in[2];
  const float* W1  = (const float*)d_in[3];
  const float* al1 = (const float*)d_in[4];
  const float* ar1 = (const float*)d_in[5];
  const float* W2  = (const float*)d_in[6];
  const float* al2 = (const float*)d_in[7];
  const float* ar2 = (const float*)d_in[8];
  float* out = (float*)d_out;

  // workspace layout
  float* ws = (float*)d_ws;
  float* el = ws;                           // NNODES*HH
  float* er = el + NNODES * HH;             // NNODES*HH
  int* deg     = (int*)(er + NNODES * HH);  // NNODES
  int* off     = deg + NNODES;              // NNODES+1
  int* cursor  = off + NNODES + 1;          // NNODES
  int* bsum    = cursor + NNODES;           // 256
  int* csr_src = bsum + 256;                // NEDGES
  uintptr_t p = ((uintptr_t)(csr_src + NEDGES) + 63) & ~(uintptr_t)63;
  _Float16* featb = (_Float16*)p;                  // NNODES*256 f16 (25.6 MB)
  _Float16* Apr = featb + (size_t)NNODES * 256;
  Apr = (_Float16*)(((uintptr_t)Apr + 63) & ~(uintptr_t)63);  // MPAD*256 f16 (L2 input)
  _Float16* Bpr1 = Apr + (size_t)MPAD * 256;       // 256*512 f16
  _Float16* Bpr2 = Bpr1 + 256 * 512;               // 256*256 f16

  const int edgeBlocks = (NEDGES + 255) / 256;

  // ---------- CSR build (shared by both layers) ----------
  hipMemsetAsync(deg, 0, NNODES * sizeof(int), stream);
  hist_kernel<<<edgeBlocks, 256, 0, stream>>>(dst, deg);
  scan_block_kernel<<<NB, 256, 0, stream>>>(deg, off, bsum);
  scan_top_kernel<<<1, 256, 0, stream>>>(bsum);
  scan_add_kernel<<<NB, 256, 0, stream>>>(off, bsum, cursor);
  scatter_kernel<<<edgeBlocks, 256, 0, stream>>>(src, dst, cursor, csr_src);

  // ---------- prep (weights only; x conversion fused into GEMM1) ----------
  prep_w_kernel<<<768, 256, 0, stream>>>(W1, W2, Bpr1, Bpr2);

  // ---------- layer 1 : K=512, A = x (f32, read once) ----------
  mfma_gemm_kernel<1><<<MPAD / 128, 512, 0, stream>>>(x, Bpr1, featb, al1, ar1, el, er, NNODES, 512);
  gat_agg_kernel<1><<<NNODES / 4, 256, 0, stream>>>(off, csr_src, el, er, featb, nullptr, Apr);

  // ---------- layer 2 : K=256, A = Apr (f16) ----------
  mfma_gemm_kernel<0><<<MPAD / 128, 512, 0, stream>>>(Apr, Bpr2, featb, al2, ar2, el, er, NNODES, 256);
  gat_agg_kernel<2><<<NNODES / 4, 256, 0, stream>>>(off, csr_src, el, er, featb, out, nullptr);
}